// Round 8
// baseline (139.244 us; speedup 1.0000x reference)
//
#include <hip/hip_runtime.h>
#include <math.h>

#define NN 8
#define CC 4
#define FF 257
#define TT 2000
#define BB 8
#define MM 80
#define EPSF 1e-5f
#define VSTR 260   // 16B-aligned rows; bank offset 4/row -> conflict-free patterns below
#define T4N 500    // TT/4
#define TTILE 8
#define NCHUNK 250 // TT/TTILE

typedef float v2f __attribute__((ext_vector_type(2)));

__device__ __forceinline__ float fsqrt_fast(float x) { return __builtin_amdgcn_sqrtf(x); }
__device__ __forceinline__ float flog_fast(float x)  { return __builtin_amdgcn_logf(x) * 0.69314718055994531f; }
__device__ __forceinline__ v2f sqrt2(v2f m) {
    v2f r; r.x = __builtin_amdgcn_sqrtf(m.x); r.y = __builtin_amdgcn_sqrtf(m.y); return r;
}

// ---------------- kernel 1: beamform q,k and reduce s partials ----------------
// grid (NN*FF, 2), block 256. Each thread: 4 consecutive t via float4, pk-math over t-pairs.
__global__ __launch_bounds__(256) void k_beam_s(
    const float* __restrict__ xr_g, const float* __restrict__ xi_g,
    const float* __restrict__ wq_r, const float* __restrict__ wq_i,
    const float* __restrict__ wk_r, const float* __restrict__ wk_i,
    float* __restrict__ s_buf)
{
    int nf = blockIdx.x;
    int n = nf / FF, f = nf % FF;
    int t4 = blockIdx.y * 256 + threadIdx.x;

    float part[BB];
#pragma unroll
    for (int b = 0; b < BB; ++b) part[b] = 0.f;

    if (t4 < T4N) {
        const float* xr_base = xr_g + ((size_t)(n*CC)*FF + f) * TT + t4*4;
        const float* xi_base = xi_g + ((size_t)(n*CC)*FF + f) * TT + t4*4;
        v2f xr2[CC][2], xi2[CC][2];
#pragma unroll
        for (int c = 0; c < CC; ++c) {
            float4 r4 = *reinterpret_cast<const float4*>(xr_base + (size_t)c*FF*TT);
            float4 i4 = *reinterpret_cast<const float4*>(xi_base + (size_t)c*FF*TT);
            xr2[c][0].x = r4.x; xr2[c][0].y = r4.y; xr2[c][1].x = r4.z; xr2[c][1].y = r4.w;
            xi2[c][0].x = i4.x; xi2[c][0].y = i4.y; xi2[c][1].x = i4.z; xi2[c][1].y = i4.w;
        }

        const float4 qr4 = *reinterpret_cast<const float4*>(&wq_r[f*CC]);  // f block-uniform -> s_load
        const float4 qi4 = *reinterpret_cast<const float4*>(&wq_i[f*CC]);

        v2f qq[2];
#pragma unroll
        for (int p = 0; p < 2; ++p) {
            v2f qr = xr2[0][p]*qr4.x + xr2[1][p]*qr4.y + xr2[2][p]*qr4.z + xr2[3][p]*qr4.w
                   - xi2[0][p]*qi4.x - xi2[1][p]*qi4.y - xi2[2][p]*qi4.z - xi2[3][p]*qi4.w;
            v2f qi = xi2[0][p]*qr4.x + xi2[1][p]*qr4.y + xi2[2][p]*qr4.z + xi2[3][p]*qr4.w
                   + xr2[0][p]*qi4.x + xr2[1][p]*qi4.y + xr2[2][p]*qi4.z + xr2[3][p]*qi4.w;
            qq[p] = qr*qr + qi*qi + EPSF;
        }

#pragma unroll
        for (int b = 0; b < BB; ++b) {
            const float4 wr4 = *reinterpret_cast<const float4*>(&wk_r[(f*BB + b)*CC]);
            const float4 wi4 = *reinterpret_cast<const float4*>(&wk_i[(f*BB + b)*CC]);
            v2f acc; acc.x = 0.f; acc.y = 0.f;
#pragma unroll
            for (int p = 0; p < 2; ++p) {
                v2f kr = xr2[0][p]*wr4.x + xr2[1][p]*wr4.y + xr2[2][p]*wr4.z + xr2[3][p]*wr4.w
                       - xi2[0][p]*wi4.x - xi2[1][p]*wi4.y - xi2[2][p]*wi4.z - xi2[3][p]*wi4.w;
                v2f ki = xi2[0][p]*wr4.x + xi2[1][p]*wr4.y + xi2[2][p]*wr4.z + xi2[3][p]*wr4.w
                       + xr2[0][p]*wi4.x + xr2[1][p]*wi4.y + xr2[2][p]*wi4.z + xr2[3][p]*wi4.w;
                v2f kk = kr*kr + ki*ki + EPSF;
                acc += sqrt2(qq[p] * kk);   // sqrt(qq)*sqrt(kk) fused
            }
            part[b] = acc.x + acc.y;
        }
    }

    __shared__ float red[4][BB];
    int lane = threadIdx.x & 63, wv = threadIdx.x >> 6;
#pragma unroll
    for (int b = 0; b < BB; ++b) {
        float v = part[b];
#pragma unroll
        for (int m = 32; m >= 1; m >>= 1) v += __shfl_xor(v, m);
        if (lane == 0) red[wv][b] = v;
    }
    __syncthreads();
    if (threadIdx.x < BB) {
        float v = red[0][threadIdx.x] + red[1][threadIdx.x]
                + red[2][threadIdx.x] + red[3][threadIdx.x];
        int bin = (blockIdx.x * 2 + blockIdx.y) & 15;
        atomicAdd(&s_buf[bin*64 + n*BB + threadIdx.x], v);
    }
}

// ---------------- kernel 2: softmax over B per n (sums 16 bins) ----------------
__global__ void k_softmax(const float* __restrict__ s_buf, float* __restrict__ w_buf)
{
    int tid = threadIdx.x;
    if (tid < NN*BB) {
        float v = 0.f;
#pragma unroll
        for (int j = 0; j < 16; ++j) v += s_buf[j*64 + tid];
        v *= (1.0f / TT);
        float mx = v;
#pragma unroll
        for (int m = 4; m >= 1; m >>= 1) mx = fmaxf(mx, __shfl_xor(mx, m));
        float e = expf(v - mx);
        float sm = e;
#pragma unroll
        for (int m = 4; m >= 1; m >>= 1) sm += __shfl_xor(sm, m);
        w_buf[tid] = e / sm;
    }
}

// ---------------- kernel 2b: repack proj_w into padded stride-260 ----------------
__global__ void k_prep(const float* __restrict__ proj_w, float* __restrict__ proj_pad)
{
    int i = blockIdx.x * 256 + threadIdx.x;
    if (i < MM * 260) {
        int m = i / 260, f = i % 260;
        proj_pad[i] = (f < FF) ? proj_w[m*FF + f] : 0.f;
    }
}

// ---------------- kernel 3 (FUSED): v from x -> LDS, project, relu, log, BN partials ----
// grid (NN, 250), block 256, t-tile = 8 (250*8 = 2000, no tail).
// Fill: f = tid (one f per thread, weights loaded ONCE); x as 2 float4 per (c,r/i) = 32B/lane.
// Proj: tl = tid&7 (t), fg = tid>>3 (0..31); even fg: 3 m, odd fg: 2 m  (16*3+16*2 = 80).
__global__ __launch_bounds__(256, 4) void k_vproj(
    const float* __restrict__ xr_g, const float* __restrict__ xi_g,
    const float* __restrict__ wv_r, const float* __restrict__ wv_i,
    const float* __restrict__ w_buf, const float* __restrict__ proj_pad,
    float* __restrict__ out, double* __restrict__ bn_sum, double* __restrict__ bn_sumsq)
{
    __shared__ float v_lds[TTILE * VSTR];
    int n = blockIdx.x, chunk = blockIdx.y;
    int t0 = chunk * TTILE;
    int tid = threadIdx.x;

    float wn[BB];
#pragma unroll
    for (int b = 0; b < BB; ++b) wn[b] = w_buf[n*BB + b];   // n uniform -> scalar

    // zero pad columns f = 257..259 (8 t x 3 f = 24 entries)
    if (tid < TTILE*3) {
        int t = tid / 3, fp = FF + tid % 3;
        v_lds[t*VSTR + fp] = 0.f;
    }

    // f = 256 column: lanes 0..7, one t each (scalar) — issued early
    if (tid < TTILE) {
        int t = t0 + tid;
        float xr[CC], xi[CC];
#pragma unroll
        for (int c = 0; c < CC; ++c) {
            size_t base = ((size_t)(n*CC + c)*FF + 256)*TT + t;
            xr[c] = xr_g[base];
            xi[c] = xi_g[base];
        }
        float v = 0.f;
#pragma unroll
        for (int b = 0; b < BB; ++b) {
            const float4 wr4 = *reinterpret_cast<const float4*>(&wv_r[(256*BB + b)*CC]);
            const float4 wi4 = *reinterpret_cast<const float4*>(&wv_i[(256*BB + b)*CC]);
            float vr = xr[0]*wr4.x + xr[1]*wr4.y + xr[2]*wr4.z + xr[3]*wr4.w
                     - xi[0]*wi4.x - xi[1]*wi4.y - xi[2]*wi4.z - xi[3]*wi4.w;
            float vi = xi[0]*wr4.x + xi[1]*wr4.y + xi[2]*wr4.z + xi[3]*wr4.w
                     + xr[0]*wi4.x + xr[1]*wi4.y + xr[2]*wi4.z + xr[3]*wi4.w;
            v += wn[b] * fsqrt_fast(vr*vr + vi*vi + EPSF);
        }
        v_lds[tid*VSTR + 256] = v;
    }

    // ---- main fill: f = tid, 8 t per thread ----
    {
        int f = tid;
        v2f xr2[CC][4], xi2[CC][4];   // 4 t-pairs
#pragma unroll
        for (int c = 0; c < CC; ++c) {
            size_t base = ((size_t)(n*CC + c)*FF + f)*TT + t0;
            float4 a = *reinterpret_cast<const float4*>(xr_g + base);
            float4 b4 = *reinterpret_cast<const float4*>(xr_g + base + 4);
            float4 d = *reinterpret_cast<const float4*>(xi_g + base);
            float4 e = *reinterpret_cast<const float4*>(xi_g + base + 4);
            xr2[c][0].x = a.x;  xr2[c][0].y = a.y;
            xr2[c][1].x = a.z;  xr2[c][1].y = a.w;
            xr2[c][2].x = b4.x; xr2[c][2].y = b4.y;
            xr2[c][3].x = b4.z; xr2[c][3].y = b4.w;
            xi2[c][0].x = d.x;  xi2[c][0].y = d.y;
            xi2[c][1].x = d.z;  xi2[c][1].y = d.w;
            xi2[c][2].x = e.x;  xi2[c][2].y = e.y;
            xi2[c][3].x = e.z;  xi2[c][3].y = e.w;
        }

        v2f vo[4];
#pragma unroll
        for (int p = 0; p < 4; ++p) { vo[p].x = 0.f; vo[p].y = 0.f; }

#pragma unroll 2
        for (int b = 0; b < BB; ++b) {
            const float4 wr4 = *reinterpret_cast<const float4*>(&wv_r[(f*BB + b)*CC]);
            const float4 wi4 = *reinterpret_cast<const float4*>(&wv_i[(f*BB + b)*CC]);
            float wnb = wn[b];
#pragma unroll
            for (int p = 0; p < 4; ++p) {
                v2f vr = xr2[0][p]*wr4.x + xr2[1][p]*wr4.y + xr2[2][p]*wr4.z + xr2[3][p]*wr4.w
                       - xi2[0][p]*wi4.x - xi2[1][p]*wi4.y - xi2[2][p]*wi4.z - xi2[3][p]*wi4.w;
                v2f vi = xi2[0][p]*wr4.x + xi2[1][p]*wr4.y + xi2[2][p]*wr4.z + xi2[3][p]*wr4.w
                       + xr2[0][p]*wi4.x + xr2[1][p]*wi4.y + xr2[2][p]*wi4.z + xr2[3][p]*wi4.w;
                vo[p] += wnb * sqrt2(vr*vr + vi*vi + EPSF);
            }
        }
#pragma unroll
        for (int p = 0; p < 4; ++p) {
            v_lds[(2*p + 0)*VSTR + f] = vo[p].x;
            v_lds[(2*p + 1)*VSTR + f] = vo[p].y;
        }
    }
    __syncthreads();

    // ---- proj stage ----
    int tl = tid & 7, fg = tid >> 3;
    int mstart = (fg >> 1)*5 + ((fg & 1) ? 3 : 0);
    bool three = !(fg & 1);
    v2f a0, a1, a2;
    a0.x = 0.f; a0.y = 0.f; a1.x = 0.f; a1.y = 0.f; a2.x = 0.f; a2.y = 0.f;
    const float* pp = proj_pad + mstart*260;
#pragma unroll 4
    for (int f4 = 0; f4 < 260; f4 += 4) {
        float4 vv = *reinterpret_cast<const float4*>(&v_lds[tl*VSTR + f4]);  // broadcast in fg-group
        v2f v0, v1;
        v0.x = vv.x; v0.y = vv.y; v1.x = vv.z; v1.y = vv.w;
        float4 p0 = *reinterpret_cast<const float4*>(&pp[f4]);
        float4 p1 = *reinterpret_cast<const float4*>(&pp[260 + f4]);
        {
            v2f q0, q1; q0.x = p0.x; q0.y = p0.y; q1.x = p0.z; q1.y = p0.w;
            a0 += v0*q0 + v1*q1;
        }
        {
            v2f q0, q1; q0.x = p1.x; q0.y = p1.y; q1.x = p1.z; q1.y = p1.w;
            a1 += v0*q0 + v1*q1;
        }
        if (three) {
            float4 p2 = *reinterpret_cast<const float4*>(&pp[520 + f4]);
            v2f q0, q1; q0.x = p2.x; q0.y = p2.y; q1.x = p2.z; q1.y = p2.w;
            a2 += v0*q0 + v1*q1;
        }
    }

    int t = t0 + tl;
    int bin = chunk & 15;
    float accs[3];
    accs[0] = a0.x + a0.y; accs[1] = a1.x + a1.y; accs[2] = a2.x + a2.y;
#pragma unroll
    for (int j = 0; j < 3; ++j) {
        if (j == 2 && !three) break;
        int m = mstart + j;
        float r = flog_fast(fmaxf(accs[j], 0.f) + EPSF);
        float s1 = r, s2 = r*r;
#pragma unroll
        for (int msk = 4; msk >= 1; msk >>= 1) {   // reduce over 8-lane tl group
            s1 += __shfl_xor(s1, msk);
            s2 += __shfl_xor(s2, msk);
        }
        out[((size_t)n*TT + t)*MM + m] = r;
        if (tl == 0) {
            atomicAdd(&bn_sum[bin*MM + m], (double)s1);
            atomicAdd(&bn_sumsq[bin*MM + m], (double)s2);
        }
    }
}

// ---------------- kernel 4a: BN finalize (sums 16 bins) ----------------
__global__ void k_bnprep(const double* __restrict__ bn_sum, const double* __restrict__ bn_sumsq,
                         const float* __restrict__ gamma, const float* __restrict__ beta,
                         float* __restrict__ scale, float* __restrict__ shift)
{
    int m = threadIdx.x;
    if (m < MM) {
        double s = 0.0, q = 0.0;
#pragma unroll
        for (int j = 0; j < 16; ++j) { s += bn_sum[j*MM + m]; q += bn_sumsq[j*MM + m]; }
        double inv = 1.0 / (double)(NN * TT);
        double mu = s * inv;
        double var = q * inv - mu * mu;
        float sc = gamma[m] * rsqrtf((float)var + EPSF);
        scale[m] = sc;
        shift[m] = beta[m] - (float)mu * sc;
    }
}

// ---------------- kernel 4b: BN apply in-place (float4) ----------------
__global__ __launch_bounds__(256) void k_bnapply(float* __restrict__ out,
                                                 const float* __restrict__ scale,
                                                 const float* __restrict__ shift)
{
    int i4 = blockIdx.x * 256 + threadIdx.x;
    if (i4 < NN*TT*MM/4) {
        float4 v = *reinterpret_cast<const float4*>(&out[i4*4]);
        int m = (i4*4) % MM;
        v.x = v.x*scale[m+0] + shift[m+0];
        v.y = v.y*scale[m+1] + shift[m+1];
        v.z = v.z*scale[m+2] + shift[m+2];
        v.w = v.w*scale[m+3] + shift[m+3];
        *reinterpret_cast<float4*>(&out[i4*4]) = v;
    }
}

extern "C" void kernel_launch(void* const* d_in, const int* in_sizes, int n_in,
                              void* d_out, int out_size, void* d_ws, size_t ws_size,
                              hipStream_t stream)
{
    const float* x_real   = (const float*)d_in[0];
    const float* x_imag   = (const float*)d_in[1];
    const float* wq_r     = (const float*)d_in[2];
    const float* wq_i     = (const float*)d_in[3];
    const float* wk_r     = (const float*)d_in[4];
    const float* wk_i     = (const float*)d_in[5];
    const float* wv_r     = (const float*)d_in[6];
    const float* wv_i     = (const float*)d_in[7];
    const float* proj_w   = (const float*)d_in[8];
    const float* bn_gamma = (const float*)d_in[9];
    const float* bn_beta  = (const float*)d_in[10];
    float* out = (float*)d_out;

    char* ws = (char*)d_ws;
    float*  s_buf    = (float*)(ws + 0);        // 16 bins x 64 floats (4096 B)
    float*  w_buf    = (float*)(ws + 4096);     // 64 floats
    float*  scale    = (float*)(ws + 4352);     // 80 floats
    float*  shift    = (float*)(ws + 4672);     // 80 floats
    double* bn_sum   = (double*)(ws + 8192);    // 16 bins x 80 doubles (10240 B)
    double* bn_sumsq = (double*)(ws + 18432);   // 16 bins x 80 doubles (10240 B)
    float*  proj_pad = (float*)(ws + 28672);    // 80*260 floats (83200 B)

    hipMemsetAsync(d_ws, 0, 28672, stream);     // zero s_buf + bn bins

    k_prep<<<(MM*260 + 255)/256, 256, 0, stream>>>(proj_w, proj_pad);

    dim3 g1(NN*FF, 2);
    k_beam_s<<<g1, 256, 0, stream>>>(x_real, x_imag, wq_r, wq_i, wk_r, wk_i, s_buf);

    k_softmax<<<1, 64, 0, stream>>>(s_buf, w_buf);

    dim3 g3(NN, NCHUNK);
    k_vproj<<<g3, 256, 0, stream>>>(x_real, x_imag, wv_r, wv_i, w_buf, proj_pad,
                                    out, bn_sum, bn_sumsq);

    k_bnprep<<<1, 128, 0, stream>>>(bn_sum, bn_sumsq, bn_gamma, bn_beta, scale, shift);

    k_bnapply<<<(NN*TT*MM/4 + 255)/256, 256, 0, stream>>>(out, scale, shift);
}

// Round 9
// 123.629 us; speedup vs baseline: 1.1263x; 1.1263x over previous
//
#include <hip/hip_runtime.h>
#include <math.h>

#define NN 8
#define CC 4
#define FF 257
#define TT 2000
#define BB 8
#define MM 80
#define EPSF 1e-5f
#define VSTR 260   // 16B-aligned rows; worst-case 2-way LDS bank aliasing (free)
#define T4N 500    // TT/4
#define TTILE 8
#define NCHUNK 250 // TT/TTILE

typedef float v2f __attribute__((ext_vector_type(2)));

__device__ __forceinline__ float fsqrt_fast(float x) { return __builtin_amdgcn_sqrtf(x); }
__device__ __forceinline__ float flog_fast(float x)  { return __builtin_amdgcn_logf(x) * 0.69314718055994531f; }
__device__ __forceinline__ v2f sqrt2(v2f m) {
    v2f r; r.x = __builtin_amdgcn_sqrtf(m.x); r.y = __builtin_amdgcn_sqrtf(m.y); return r;
}

// ---------------- kernel 1: beamform q,k and reduce s partials ----------------
// grid (NN*FF, 2), block 256. Each thread: 4 consecutive t via float4, pk-math over t-pairs.
__global__ __launch_bounds__(256) void k_beam_s(
    const float* __restrict__ xr_g, const float* __restrict__ xi_g,
    const float* __restrict__ wq_r, const float* __restrict__ wq_i,
    const float* __restrict__ wk_r, const float* __restrict__ wk_i,
    float* __restrict__ s_buf)
{
    int nf = blockIdx.x;
    int n = nf / FF, f = nf % FF;
    int t4 = blockIdx.y * 256 + threadIdx.x;

    float part[BB];
#pragma unroll
    for (int b = 0; b < BB; ++b) part[b] = 0.f;

    if (t4 < T4N) {
        const float* xr_base = xr_g + ((size_t)(n*CC)*FF + f) * TT + t4*4;
        const float* xi_base = xi_g + ((size_t)(n*CC)*FF + f) * TT + t4*4;
        v2f xr2[CC][2], xi2[CC][2];
#pragma unroll
        for (int c = 0; c < CC; ++c) {
            float4 r4 = *reinterpret_cast<const float4*>(xr_base + (size_t)c*FF*TT);
            float4 i4 = *reinterpret_cast<const float4*>(xi_base + (size_t)c*FF*TT);
            xr2[c][0].x = r4.x; xr2[c][0].y = r4.y; xr2[c][1].x = r4.z; xr2[c][1].y = r4.w;
            xi2[c][0].x = i4.x; xi2[c][0].y = i4.y; xi2[c][1].x = i4.z; xi2[c][1].y = i4.w;
        }

        const float4 qr4 = *reinterpret_cast<const float4*>(&wq_r[f*CC]);  // f block-uniform -> s_load
        const float4 qi4 = *reinterpret_cast<const float4*>(&wq_i[f*CC]);

        v2f qq[2];
#pragma unroll
        for (int p = 0; p < 2; ++p) {
            v2f qr = xr2[0][p]*qr4.x + xr2[1][p]*qr4.y + xr2[2][p]*qr4.z + xr2[3][p]*qr4.w
                   - xi2[0][p]*qi4.x - xi2[1][p]*qi4.y - xi2[2][p]*qi4.z - xi2[3][p]*qi4.w;
            v2f qi = xi2[0][p]*qr4.x + xi2[1][p]*qr4.y + xi2[2][p]*qr4.z + xi2[3][p]*qr4.w
                   + xr2[0][p]*qi4.x + xr2[1][p]*qi4.y + xr2[2][p]*qi4.z + xr2[3][p]*qi4.w;
            qq[p] = qr*qr + qi*qi + EPSF;
        }

#pragma unroll
        for (int b = 0; b < BB; ++b) {
            const float4 wr4 = *reinterpret_cast<const float4*>(&wk_r[(f*BB + b)*CC]);
            const float4 wi4 = *reinterpret_cast<const float4*>(&wk_i[(f*BB + b)*CC]);
            v2f acc; acc.x = 0.f; acc.y = 0.f;
#pragma unroll
            for (int p = 0; p < 2; ++p) {
                v2f kr = xr2[0][p]*wr4.x + xr2[1][p]*wr4.y + xr2[2][p]*wr4.z + xr2[3][p]*wr4.w
                       - xi2[0][p]*wi4.x - xi2[1][p]*wi4.y - xi2[2][p]*wi4.z - xi2[3][p]*wi4.w;
                v2f ki = xi2[0][p]*wr4.x + xi2[1][p]*wr4.y + xi2[2][p]*wr4.z + xi2[3][p]*wr4.w
                       + xr2[0][p]*wi4.x + xr2[1][p]*wi4.y + xr2[2][p]*wi4.z + xr2[3][p]*wi4.w;
                v2f kk = kr*kr + ki*ki + EPSF;
                acc += sqrt2(qq[p] * kk);   // sqrt(qq)*sqrt(kk) fused
            }
            part[b] = acc.x + acc.y;
        }
    }

    __shared__ float red[4][BB];
    int lane = threadIdx.x & 63, wv = threadIdx.x >> 6;
#pragma unroll
    for (int b = 0; b < BB; ++b) {
        float v = part[b];
#pragma unroll
        for (int m = 32; m >= 1; m >>= 1) v += __shfl_xor(v, m);
        if (lane == 0) red[wv][b] = v;
    }
    __syncthreads();
    if (threadIdx.x < BB) {
        float v = red[0][threadIdx.x] + red[1][threadIdx.x]
                + red[2][threadIdx.x] + red[3][threadIdx.x];
        int bin = (blockIdx.x * 2 + blockIdx.y) & 15;
        atomicAdd(&s_buf[bin*64 + n*BB + threadIdx.x], v);
    }
}

// ---------------- kernel 2: softmax over B per n (sums 16 bins) ----------------
__global__ void k_softmax(const float* __restrict__ s_buf, float* __restrict__ w_buf)
{
    int tid = threadIdx.x;
    if (tid < NN*BB) {
        float v = 0.f;
#pragma unroll
        for (int j = 0; j < 16; ++j) v += s_buf[j*64 + tid];
        v *= (1.0f / TT);
        float mx = v;
#pragma unroll
        for (int m = 4; m >= 1; m >>= 1) mx = fmaxf(mx, __shfl_xor(mx, m));
        float e = expf(v - mx);
        float sm = e;
#pragma unroll
        for (int m = 4; m >= 1; m >>= 1) sm += __shfl_xor(sm, m);
        w_buf[tid] = e / sm;
    }
}

// ---------------- kernel 2b: repack proj_w into padded stride-260 ----------------
__global__ void k_prep(const float* __restrict__ proj_w, float* __restrict__ proj_pad)
{
    int i = blockIdx.x * 256 + threadIdx.x;
    if (i < MM * 260) {
        int m = i / 260, f = i % 260;
        proj_pad[i] = (f < FF) ? proj_w[m*FF + f] : 0.f;
    }
}

// ---------------- kernel 3a: v[n,f,t] = sum_b w_b * |beam_v| (streaming, pk) ----------------
// grid (NN*FF, 2), block 256; f block-uniform -> weight loads are scalar; t coalesced.
__global__ __launch_bounds__(256) void k_vcompute(
    const float* __restrict__ xr_g, const float* __restrict__ xi_g,
    const float* __restrict__ wv_r, const float* __restrict__ wv_i,
    const float* __restrict__ w_buf, float* __restrict__ vbuf)
{
    int nf = blockIdx.x;
    int n = nf / FF, f = nf % FF;
    int t4 = blockIdx.y * 256 + threadIdx.x;
    if (t4 >= T4N) return;

    const float* xr_base = xr_g + ((size_t)(n*CC)*FF + f) * TT + t4*4;
    const float* xi_base = xi_g + ((size_t)(n*CC)*FF + f) * TT + t4*4;
    v2f xr2[CC][2], xi2[CC][2];
#pragma unroll
    for (int c = 0; c < CC; ++c) {
        float4 r4 = *reinterpret_cast<const float4*>(xr_base + (size_t)c*FF*TT);
        float4 i4 = *reinterpret_cast<const float4*>(xi_base + (size_t)c*FF*TT);
        xr2[c][0].x = r4.x; xr2[c][0].y = r4.y; xr2[c][1].x = r4.z; xr2[c][1].y = r4.w;
        xi2[c][0].x = i4.x; xi2[c][0].y = i4.y; xi2[c][1].x = i4.z; xi2[c][1].y = i4.w;
    }

    v2f vo[2];
    vo[0].x = 0.f; vo[0].y = 0.f; vo[1].x = 0.f; vo[1].y = 0.f;
#pragma unroll
    for (int b = 0; b < BB; ++b) {
        float wn = w_buf[n*BB + b];                      // n uniform -> scalar
        const float4 wr4 = *reinterpret_cast<const float4*>(&wv_r[(f*BB + b)*CC]);
        const float4 wi4 = *reinterpret_cast<const float4*>(&wv_i[(f*BB + b)*CC]);
#pragma unroll
        for (int p = 0; p < 2; ++p) {
            v2f vr = xr2[0][p]*wr4.x + xr2[1][p]*wr4.y + xr2[2][p]*wr4.z + xr2[3][p]*wr4.w
                   - xi2[0][p]*wi4.x - xi2[1][p]*wi4.y - xi2[2][p]*wi4.z - xi2[3][p]*wi4.w;
            v2f vi = xi2[0][p]*wr4.x + xi2[1][p]*wr4.y + xi2[2][p]*wr4.z + xi2[3][p]*wr4.w
                   + xr2[0][p]*wi4.x + xr2[1][p]*wi4.y + xr2[2][p]*wi4.z + xr2[3][p]*wi4.w;
            vo[p] += wn * sqrt2(vr*vr + vi*vi + EPSF);
        }
    }
    float4 o; o.x = vo[0].x; o.y = vo[0].y; o.z = vo[1].x; o.w = vo[1].y;
    *reinterpret_cast<float4*>(&vbuf[((size_t)(n*FF + f))*TT + t4*4]) = o;
}

// ---------------- kernel 3b: project, relu, log, BN partials (high occupancy) ----------------
// grid (NN, 250), block 256, t-tile 8 (250*8 = 2000). LDS tile 8t x 260f (8.3 KB).
// Fill: (fb = tid>>1, half = tid&1): one float4 (4 t) per thread x 2 iters; f=256 by tid<2.
// Proj: tl = tid&7 (t), fg = tid>>3 (0..31); even fg: 3 m, odd fg: 2 m  (16*3+16*2 = 80).
__global__ __launch_bounds__(256) void k_proj(
    const float* __restrict__ vbuf, const float* __restrict__ proj_pad,
    float* __restrict__ out, double* __restrict__ bn_sum, double* __restrict__ bn_sumsq)
{
    __shared__ float v_lds[TTILE * VSTR];
    int n = blockIdx.x, chunk = blockIdx.y;
    int t0 = chunk * TTILE;
    int tid = threadIdx.x;

    // zero pad columns f = 257..259 (8 t x 3 f = 24 entries)
    if (tid < TTILE*3) {
        int t = tid / 3, fp = FF + tid % 3;
        v_lds[t*VSTR + fp] = 0.f;
    }

    int fb = tid >> 1, half = tid & 1;
#pragma unroll
    for (int it = 0; it < 2; ++it) {
        int f = fb + 128*it;   // 0..255
        float4 vv = *reinterpret_cast<const float4*>(&vbuf[((size_t)(n*FF + f))*TT + t0 + half*4]);
        v_lds[(half*4 + 0)*VSTR + f] = vv.x;
        v_lds[(half*4 + 1)*VSTR + f] = vv.y;
        v_lds[(half*4 + 2)*VSTR + f] = vv.z;
        v_lds[(half*4 + 3)*VSTR + f] = vv.w;
    }
    if (tid < 2) {
        float4 vv = *reinterpret_cast<const float4*>(&vbuf[((size_t)(n*FF + 256))*TT + t0 + tid*4]);
        v_lds[(tid*4 + 0)*VSTR + 256] = vv.x;
        v_lds[(tid*4 + 1)*VSTR + 256] = vv.y;
        v_lds[(tid*4 + 2)*VSTR + 256] = vv.z;
        v_lds[(tid*4 + 3)*VSTR + 256] = vv.w;
    }
    __syncthreads();

    // ---- proj stage (pk-FMA, b128 LDS reads) ----
    int tl = tid & 7, fg = tid >> 3;
    int mstart = (fg >> 1)*5 + ((fg & 1) ? 3 : 0);
    bool three = !(fg & 1);
    v2f a0, a1, a2;
    a0.x = 0.f; a0.y = 0.f; a1.x = 0.f; a1.y = 0.f; a2.x = 0.f; a2.y = 0.f;
    const float* pp = proj_pad + mstart*260;
#pragma unroll 4
    for (int f4 = 0; f4 < 260; f4 += 4) {
        float4 vv = *reinterpret_cast<const float4*>(&v_lds[tl*VSTR + f4]);
        v2f v0, v1;
        v0.x = vv.x; v0.y = vv.y; v1.x = vv.z; v1.y = vv.w;
        float4 p0 = *reinterpret_cast<const float4*>(&pp[f4]);
        float4 p1 = *reinterpret_cast<const float4*>(&pp[260 + f4]);
        {
            v2f q0, q1; q0.x = p0.x; q0.y = p0.y; q1.x = p0.z; q1.y = p0.w;
            a0 += v0*q0 + v1*q1;
        }
        {
            v2f q0, q1; q0.x = p1.x; q0.y = p1.y; q1.x = p1.z; q1.y = p1.w;
            a1 += v0*q0 + v1*q1;
        }
        if (three) {
            float4 p2 = *reinterpret_cast<const float4*>(&pp[520 + f4]);
            v2f q0, q1; q0.x = p2.x; q0.y = p2.y; q1.x = p2.z; q1.y = p2.w;
            a2 += v0*q0 + v1*q1;
        }
    }

    int t = t0 + tl;
    int bin = chunk & 15;
    float accs[3];
    accs[0] = a0.x + a0.y; accs[1] = a1.x + a1.y; accs[2] = a2.x + a2.y;
#pragma unroll
    for (int j = 0; j < 3; ++j) {
        if (j == 2 && !three) break;
        int m = mstart + j;
        float r = flog_fast(fmaxf(accs[j], 0.f) + EPSF);
        float s1 = r, s2 = r*r;
#pragma unroll
        for (int msk = 4; msk >= 1; msk >>= 1) {   // reduce over 8-lane tl group
            s1 += __shfl_xor(s1, msk);
            s2 += __shfl_xor(s2, msk);
        }
        out[((size_t)n*TT + t)*MM + m] = r;
        if (tl == 0) {
            atomicAdd(&bn_sum[bin*MM + m], (double)s1);
            atomicAdd(&bn_sumsq[bin*MM + m], (double)s2);
        }
    }
}

// ---------------- kernel 4a: BN finalize (sums 16 bins) ----------------
__global__ void k_bnprep(const double* __restrict__ bn_sum, const double* __restrict__ bn_sumsq,
                         const float* __restrict__ gamma, const float* __restrict__ beta,
                         float* __restrict__ scale, float* __restrict__ shift)
{
    int m = threadIdx.x;
    if (m < MM) {
        double s = 0.0, q = 0.0;
#pragma unroll
        for (int j = 0; j < 16; ++j) { s += bn_sum[j*MM + m]; q += bn_sumsq[j*MM + m]; }
        double inv = 1.0 / (double)(NN * TT);
        double mu = s * inv;
        double var = q * inv - mu * mu;
        float sc = gamma[m] * rsqrtf((float)var + EPSF);
        scale[m] = sc;
        shift[m] = beta[m] - (float)mu * sc;
    }
}

// ---------------- kernel 4b: BN apply in-place (float4) ----------------
__global__ __launch_bounds__(256) void k_bnapply(float* __restrict__ out,
                                                 const float* __restrict__ scale,
                                                 const float* __restrict__ shift)
{
    int i4 = blockIdx.x * 256 + threadIdx.x;
    if (i4 < NN*TT*MM/4) {
        float4 v = *reinterpret_cast<const float4*>(&out[i4*4]);
        int m = (i4*4) % MM;
        v.x = v.x*scale[m+0] + shift[m+0];
        v.y = v.y*scale[m+1] + shift[m+1];
        v.z = v.z*scale[m+2] + shift[m+2];
        v.w = v.w*scale[m+3] + shift[m+3];
        *reinterpret_cast<float4*>(&out[i4*4]) = v;
    }
}

extern "C" void kernel_launch(void* const* d_in, const int* in_sizes, int n_in,
                              void* d_out, int out_size, void* d_ws, size_t ws_size,
                              hipStream_t stream)
{
    const float* x_real   = (const float*)d_in[0];
    const float* x_imag   = (const float*)d_in[1];
    const float* wq_r     = (const float*)d_in[2];
    const float* wq_i     = (const float*)d_in[3];
    const float* wk_r     = (const float*)d_in[4];
    const float* wk_i     = (const float*)d_in[5];
    const float* wv_r     = (const float*)d_in[6];
    const float* wv_i     = (const float*)d_in[7];
    const float* proj_w   = (const float*)d_in[8];
    const float* bn_gamma = (const float*)d_in[9];
    const float* bn_beta  = (const float*)d_in[10];
    float* out = (float*)d_out;

    char* ws = (char*)d_ws;
    float*  s_buf    = (float*)(ws + 0);        // 16 bins x 64 floats (4096 B)
    float*  w_buf    = (float*)(ws + 4096);     // 64 floats
    float*  scale    = (float*)(ws + 4352);     // 80 floats
    float*  shift    = (float*)(ws + 4672);     // 80 floats
    double* bn_sum   = (double*)(ws + 8192);    // 16 bins x 80 doubles (10240 B)
    double* bn_sumsq = (double*)(ws + 18432);   // 16 bins x 80 doubles (10240 B)
    float*  proj_pad = (float*)(ws + 28672);    // 80*260 floats (83200 B)
    float*  vbuf     = (float*)(ws + 112640);   // 8*257*2000 floats (16448000 B)

    hipMemsetAsync(d_ws, 0, 28672, stream);     // zero s_buf + bn bins

    k_prep<<<(MM*260 + 255)/256, 256, 0, stream>>>(proj_w, proj_pad);

    dim3 g1(NN*FF, 2);
    k_beam_s<<<g1, 256, 0, stream>>>(x_real, x_imag, wq_r, wq_i, wk_r, wk_i, s_buf);

    k_softmax<<<1, 64, 0, stream>>>(s_buf, w_buf);

    k_vcompute<<<g1, 256, 0, stream>>>(x_real, x_imag, wv_r, wv_i, w_buf, vbuf);

    dim3 g3(NN, NCHUNK);
    k_proj<<<g3, 256, 0, stream>>>(vbuf, proj_pad, out, bn_sum, bn_sumsq);

    k_bnprep<<<1, 128, 0, stream>>>(bn_sum, bn_sumsq, bn_gamma, bn_beta, scale, shift);

    k_bnapply<<<(NN*TT*MM/4 + 255)/256, 256, 0, stream>>>(out, scale, shift);
}

// Round 10
// 101.206 us; speedup vs baseline: 1.3758x; 1.2216x over previous
//
#include <hip/hip_runtime.h>
#include <math.h>

#define NN 8
#define CC 4
#define FF 257
#define TT 2000
#define BB 8
#define MM 80
#define EPSF 1e-5f
#define T4N 500    // TT/4
#define PTILE 32   // t per block in k_proj
#define PSTR 260   // LDS row stride: 16B-aligned; t-stride 260%32=4 banks -> conflict-free tl reads
#define PCHUNK 63  // ceil(2000/32)

typedef float v2f __attribute__((ext_vector_type(2)));

__device__ __forceinline__ float fsqrt_fast(float x) { return __builtin_amdgcn_sqrtf(x); }
__device__ __forceinline__ float flog_fast(float x)  { return __builtin_amdgcn_logf(x) * 0.69314718055994531f; }
__device__ __forceinline__ v2f sqrt2(v2f m) {
    v2f r; r.x = __builtin_amdgcn_sqrtf(m.x); r.y = __builtin_amdgcn_sqrtf(m.y); return r;
}

// ---------------- kernel 1: beamform q,k and reduce s partials ----------------
// grid (NN*FF, 2), block 256. Each thread: 4 consecutive t via float4, pk-math over t-pairs.
__global__ __launch_bounds__(256) void k_beam_s(
    const float* __restrict__ xr_g, const float* __restrict__ xi_g,
    const float* __restrict__ wq_r, const float* __restrict__ wq_i,
    const float* __restrict__ wk_r, const float* __restrict__ wk_i,
    float* __restrict__ s_buf)
{
    int nf = blockIdx.x;
    int n = nf / FF, f = nf % FF;
    int t4 = blockIdx.y * 256 + threadIdx.x;

    float part[BB];
#pragma unroll
    for (int b = 0; b < BB; ++b) part[b] = 0.f;

    if (t4 < T4N) {
        const float* xr_base = xr_g + ((size_t)(n*CC)*FF + f) * TT + t4*4;
        const float* xi_base = xi_g + ((size_t)(n*CC)*FF + f) * TT + t4*4;
        v2f xr2[CC][2], xi2[CC][2];
#pragma unroll
        for (int c = 0; c < CC; ++c) {
            float4 r4 = *reinterpret_cast<const float4*>(xr_base + (size_t)c*FF*TT);
            float4 i4 = *reinterpret_cast<const float4*>(xi_base + (size_t)c*FF*TT);
            xr2[c][0].x = r4.x; xr2[c][0].y = r4.y; xr2[c][1].x = r4.z; xr2[c][1].y = r4.w;
            xi2[c][0].x = i4.x; xi2[c][0].y = i4.y; xi2[c][1].x = i4.z; xi2[c][1].y = i4.w;
        }

        const float4 qr4 = *reinterpret_cast<const float4*>(&wq_r[f*CC]);  // f block-uniform -> s_load
        const float4 qi4 = *reinterpret_cast<const float4*>(&wq_i[f*CC]);

        v2f qq[2];
#pragma unroll
        for (int p = 0; p < 2; ++p) {
            v2f qr = xr2[0][p]*qr4.x + xr2[1][p]*qr4.y + xr2[2][p]*qr4.z + xr2[3][p]*qr4.w
                   - xi2[0][p]*qi4.x - xi2[1][p]*qi4.y - xi2[2][p]*qi4.z - xi2[3][p]*qi4.w;
            v2f qi = xi2[0][p]*qr4.x + xi2[1][p]*qr4.y + xi2[2][p]*qr4.z + xi2[3][p]*qr4.w
                   + xr2[0][p]*qi4.x + xr2[1][p]*qi4.y + xr2[2][p]*qi4.z + xr2[3][p]*qi4.w;
            qq[p] = qr*qr + qi*qi + EPSF;
        }

#pragma unroll
        for (int b = 0; b < BB; ++b) {
            const float4 wr4 = *reinterpret_cast<const float4*>(&wk_r[(f*BB + b)*CC]);
            const float4 wi4 = *reinterpret_cast<const float4*>(&wk_i[(f*BB + b)*CC]);
            v2f acc; acc.x = 0.f; acc.y = 0.f;
#pragma unroll
            for (int p = 0; p < 2; ++p) {
                v2f kr = xr2[0][p]*wr4.x + xr2[1][p]*wr4.y + xr2[2][p]*wr4.z + xr2[3][p]*wr4.w
                       - xi2[0][p]*wi4.x - xi2[1][p]*wi4.y - xi2[2][p]*wi4.z - xi2[3][p]*wi4.w;
                v2f ki = xi2[0][p]*wr4.x + xi2[1][p]*wr4.y + xi2[2][p]*wr4.z + xi2[3][p]*wr4.w
                       + xr2[0][p]*wi4.x + xr2[1][p]*wi4.y + xr2[2][p]*wi4.z + xr2[3][p]*wi4.w;
                v2f kk = kr*kr + ki*ki + EPSF;
                acc += sqrt2(qq[p] * kk);   // sqrt(qq)*sqrt(kk) fused
            }
            part[b] = acc.x + acc.y;
        }
    }

    __shared__ float red[4][BB];
    int lane = threadIdx.x & 63, wv = threadIdx.x >> 6;
#pragma unroll
    for (int b = 0; b < BB; ++b) {
        float v = part[b];
#pragma unroll
        for (int m = 32; m >= 1; m >>= 1) v += __shfl_xor(v, m);
        if (lane == 0) red[wv][b] = v;
    }
    __syncthreads();
    if (threadIdx.x < BB) {
        float v = red[0][threadIdx.x] + red[1][threadIdx.x]
                + red[2][threadIdx.x] + red[3][threadIdx.x];
        int bin = (blockIdx.x * 2 + blockIdx.y) & 15;
        atomicAdd(&s_buf[bin*64 + n*BB + threadIdx.x], v);
    }
}

// ---------------- kernel 2: softmax over B per n (sums 16 bins) ----------------
__global__ void k_softmax(const float* __restrict__ s_buf, float* __restrict__ w_buf)
{
    int tid = threadIdx.x;
    if (tid < NN*BB) {
        float v = 0.f;
#pragma unroll
        for (int j = 0; j < 16; ++j) v += s_buf[j*64 + tid];
        v *= (1.0f / TT);
        float mx = v;
#pragma unroll
        for (int m = 4; m >= 1; m >>= 1) mx = fmaxf(mx, __shfl_xor(mx, m));
        float e = expf(v - mx);
        float sm = e;
#pragma unroll
        for (int m = 4; m >= 1; m >>= 1) sm += __shfl_xor(sm, m);
        w_buf[tid] = e / sm;
    }
}

// ---------------- kernel 2b: repack proj_w into padded stride-260 ----------------
__global__ void k_prep(const float* __restrict__ proj_w, float* __restrict__ proj_pad)
{
    int i = blockIdx.x * 256 + threadIdx.x;
    if (i < MM * 260) {
        int m = i / 260, f = i % 260;
        proj_pad[i] = (f < FF) ? proj_w[m*FF + f] : 0.f;
    }
}

// ---------------- kernel 3a: v[n,f,t] = sum_b w_b * |beam_v| (streaming, pk) ----------------
// grid (NN*FF, 2), block 256; f block-uniform -> weight loads are scalar; t coalesced.
__global__ __launch_bounds__(256) void k_vcompute(
    const float* __restrict__ xr_g, const float* __restrict__ xi_g,
    const float* __restrict__ wv_r, const float* __restrict__ wv_i,
    const float* __restrict__ w_buf, float* __restrict__ vbuf)
{
    int nf = blockIdx.x;
    int n = nf / FF, f = nf % FF;
    int t4 = blockIdx.y * 256 + threadIdx.x;
    if (t4 >= T4N) return;

    const float* xr_base = xr_g + ((size_t)(n*CC)*FF + f) * TT + t4*4;
    const float* xi_base = xi_g + ((size_t)(n*CC)*FF + f) * TT + t4*4;
    v2f xr2[CC][2], xi2[CC][2];
#pragma unroll
    for (int c = 0; c < CC; ++c) {
        float4 r4 = *reinterpret_cast<const float4*>(xr_base + (size_t)c*FF*TT);
        float4 i4 = *reinterpret_cast<const float4*>(xi_base + (size_t)c*FF*TT);
        xr2[c][0].x = r4.x; xr2[c][0].y = r4.y; xr2[c][1].x = r4.z; xr2[c][1].y = r4.w;
        xi2[c][0].x = i4.x; xi2[c][0].y = i4.y; xi2[c][1].x = i4.z; xi2[c][1].y = i4.w;
    }

    v2f vo[2];
    vo[0].x = 0.f; vo[0].y = 0.f; vo[1].x = 0.f; vo[1].y = 0.f;
#pragma unroll
    for (int b = 0; b < BB; ++b) {
        float wn = w_buf[n*BB + b];                      // n uniform -> scalar
        const float4 wr4 = *reinterpret_cast<const float4*>(&wv_r[(f*BB + b)*CC]);
        const float4 wi4 = *reinterpret_cast<const float4*>(&wv_i[(f*BB + b)*CC]);
#pragma unroll
        for (int p = 0; p < 2; ++p) {
            v2f vr = xr2[0][p]*wr4.x + xr2[1][p]*wr4.y + xr2[2][p]*wr4.z + xr2[3][p]*wr4.w
                   - xi2[0][p]*wi4.x - xi2[1][p]*wi4.y - xi2[2][p]*wi4.z - xi2[3][p]*wi4.w;
            v2f vi = xi2[0][p]*wr4.x + xi2[1][p]*wr4.y + xi2[2][p]*wr4.z + xi2[3][p]*wr4.w
                   + xr2[0][p]*wi4.x + xr2[1][p]*wi4.y + xr2[2][p]*wi4.z + xr2[3][p]*wi4.w;
            vo[p] += wn * sqrt2(vr*vr + vi*vi + EPSF);
        }
    }
    float4 o; o.x = vo[0].x; o.y = vo[0].y; o.z = vo[1].x; o.w = vo[1].y;
    *reinterpret_cast<float4*>(&vbuf[((size_t)(n*FF + f))*TT + t4*4]) = o;
}

// ---------------- kernel 3b: project, relu, log, BN partials (t-register-blocked) ----------------
// grid (NN, 63), block 256, t-tile 32. LDS tile 32t x 260f (33.3 KB -> 4 blocks/CU).
// Fill: tq = tid&7 (float4 slot of 32 t), fi = tid>>3; 8 iters f = fi+32k; f=256 by tid<8.
// Proj: tl = tid&7, fg = tid>>3 (0..31), each lane: 4 t (t = tl+8j) x (2 or 3) m.
//       Each proj_pad float4 loaded ONCE feeds 4 t -> 4x fewer weight loads than R9.
__global__ __launch_bounds__(256) void k_proj(
    const float* __restrict__ vbuf, const float* __restrict__ proj_pad,
    float* __restrict__ out, double* __restrict__ bn_sum, double* __restrict__ bn_sumsq)
{
    __shared__ float v_lds[PTILE * PSTR];
    int n = blockIdx.x, chunk = blockIdx.y;
    int t0 = chunk * PTILE;
    int tid = threadIdx.x;
    bool full = (t0 + PTILE <= TT);   // tail chunk (62) has only 16 valid t

    // zero pad columns f = 257..259 for all 32 t
    if (tid < PTILE*3) {
        int t = tid / 3, fp = FF + tid % 3;
        v_lds[t*PSTR + fp] = 0.f;
    }

    int tq = tid & 7, fi = tid >> 3;
    bool tqv = full || (tq < 4);
#pragma unroll
    for (int k = 0; k < 8; ++k) {
        int f = fi + 32*k;   // 0..255
        float4 vv;
        if (tqv) vv = *reinterpret_cast<const float4*>(&vbuf[((size_t)(n*FF + f))*TT + t0 + tq*4]);
        else { vv.x = 0.f; vv.y = 0.f; vv.z = 0.f; vv.w = 0.f; }
        v_lds[(tq*4 + 0)*PSTR + f] = vv.x;
        v_lds[(tq*4 + 1)*PSTR + f] = vv.y;
        v_lds[(tq*4 + 2)*PSTR + f] = vv.z;
        v_lds[(tq*4 + 3)*PSTR + f] = vv.w;
    }
    if (tid < 8) {
        float4 vv;
        if (full || tid < 4) vv = *reinterpret_cast<const float4*>(&vbuf[((size_t)(n*FF + 256))*TT + t0 + tid*4]);
        else { vv.x = 0.f; vv.y = 0.f; vv.z = 0.f; vv.w = 0.f; }
        v_lds[(tid*4 + 0)*PSTR + 256] = vv.x;
        v_lds[(tid*4 + 1)*PSTR + 256] = vv.y;
        v_lds[(tid*4 + 2)*PSTR + 256] = vv.z;
        v_lds[(tid*4 + 3)*PSTR + 256] = vv.w;
    }
    __syncthreads();

    // ---- proj: lane = (tl, fg); 4 t x 2-3 m per lane ----
    int tl = tid & 7, fg = tid >> 3;
    int mstart = (fg >> 1)*5 + ((fg & 1) ? 3 : 0);
    bool three = !(fg & 1);

    v2f acc[3][4];
#pragma unroll
    for (int mi = 0; mi < 3; ++mi)
#pragma unroll
        for (int j = 0; j < 4; ++j) { acc[mi][j].x = 0.f; acc[mi][j].y = 0.f; }

    const float* pp = proj_pad + mstart*260;
#pragma unroll 2
    for (int f4 = 0; f4 < 260; f4 += 4) {
        float4 p0 = *reinterpret_cast<const float4*>(&pp[f4]);
        float4 p1 = *reinterpret_cast<const float4*>(&pp[260 + f4]);
        v2f q00, q01, q10, q11, q20, q21;
        q00.x = p0.x; q00.y = p0.y; q01.x = p0.z; q01.y = p0.w;
        q10.x = p1.x; q10.y = p1.y; q11.x = p1.z; q11.y = p1.w;
        if (three) {
            float4 p2 = *reinterpret_cast<const float4*>(&pp[520 + f4]);
            q20.x = p2.x; q20.y = p2.y; q21.x = p2.z; q21.y = p2.w;
        }
#pragma unroll
        for (int j = 0; j < 4; ++j) {
            float4 vv = *reinterpret_cast<const float4*>(&v_lds[(tl + 8*j)*PSTR + f4]);
            v2f v0, v1;
            v0.x = vv.x; v0.y = vv.y; v1.x = vv.z; v1.y = vv.w;
            acc[0][j] += v0*q00 + v1*q01;
            acc[1][j] += v0*q10 + v1*q11;
            if (three) acc[2][j] += v0*q20 + v1*q21;
        }
    }

    int bin = chunk & 15;
#pragma unroll
    for (int mi = 0; mi < 3; ++mi) {
        if (mi == 2 && !three) break;
        int m = mstart + mi;
        float s1 = 0.f, s2 = 0.f;
#pragma unroll
        for (int j = 0; j < 4; ++j) {
            int t = t0 + tl + 8*j;
            if (t < TT) {
                float r = flog_fast(fmaxf(acc[mi][j].x + acc[mi][j].y, 0.f) + EPSF);
                s1 += r; s2 += r*r;
                out[((size_t)n*TT + t)*MM + m] = r;
            }
        }
#pragma unroll
        for (int msk = 4; msk >= 1; msk >>= 1) {   // reduce over 8-lane fg group
            s1 += __shfl_xor(s1, msk);
            s2 += __shfl_xor(s2, msk);
        }
        if (tl == 0) {
            atomicAdd(&bn_sum[bin*MM + m], (double)s1);
            atomicAdd(&bn_sumsq[bin*MM + m], (double)s2);
        }
    }
}

// ---------------- kernel 4a: BN finalize (sums 16 bins) ----------------
__global__ void k_bnprep(const double* __restrict__ bn_sum, const double* __restrict__ bn_sumsq,
                         const float* __restrict__ gamma, const float* __restrict__ beta,
                         float* __restrict__ scale, float* __restrict__ shift)
{
    int m = threadIdx.x;
    if (m < MM) {
        double s = 0.0, q = 0.0;
#pragma unroll
        for (int j = 0; j < 16; ++j) { s += bn_sum[j*MM + m]; q += bn_sumsq[j*MM + m]; }
        double inv = 1.0 / (double)(NN * TT);
        double mu = s * inv;
        double var = q * inv - mu * mu;
        float sc = gamma[m] * rsqrtf((float)var + EPSF);
        scale[m] = sc;
        shift[m] = beta[m] - (float)mu * sc;
    }
}

// ---------------- kernel 4b: BN apply in-place (float4) ----------------
__global__ __launch_bounds__(256) void k_bnapply(float* __restrict__ out,
                                                 const float* __restrict__ scale,
                                                 const float* __restrict__ shift)
{
    int i4 = blockIdx.x * 256 + threadIdx.x;
    if (i4 < NN*TT*MM/4) {
        float4 v = *reinterpret_cast<const float4*>(&out[i4*4]);
        int m = (i4*4) % MM;
        v.x = v.x*scale[m+0] + shift[m+0];
        v.y = v.y*scale[m+1] + shift[m+1];
        v.z = v.z*scale[m+2] + shift[m+2];
        v.w = v.w*scale[m+3] + shift[m+3];
        *reinterpret_cast<float4*>(&out[i4*4]) = v;
    }
}

extern "C" void kernel_launch(void* const* d_in, const int* in_sizes, int n_in,
                              void* d_out, int out_size, void* d_ws, size_t ws_size,
                              hipStream_t stream)
{
    const float* x_real   = (const float*)d_in[0];
    const float* x_imag   = (const float*)d_in[1];
    const float* wq_r     = (const float*)d_in[2];
    const float* wq_i     = (const float*)d_in[3];
    const float* wk_r     = (const float*)d_in[4];
    const float* wk_i     = (const float*)d_in[5];
    const float* wv_r     = (const float*)d_in[6];
    const float* wv_i     = (const float*)d_in[7];
    const float* proj_w   = (const float*)d_in[8];
    const float* bn_gamma = (const float*)d_in[9];
    const float* bn_beta  = (const float*)d_in[10];
    float* out = (float*)d_out;

    char* ws = (char*)d_ws;
    float*  s_buf    = (float*)(ws + 0);        // 16 bins x 64 floats (4096 B)
    float*  w_buf    = (float*)(ws + 4096);     // 64 floats
    float*  scale    = (float*)(ws + 4352);     // 80 floats
    float*  shift    = (float*)(ws + 4672);     // 80 floats
    double* bn_sum   = (double*)(ws + 8192);    // 16 bins x 80 doubles (10240 B)
    double* bn_sumsq = (double*)(ws + 18432);   // 16 bins x 80 doubles (10240 B)
    float*  proj_pad = (float*)(ws + 28672);    // 80*260 floats (83200 B)
    float*  vbuf     = (float*)(ws + 112640);   // 8*257*2000 floats (16448000 B)

    hipMemsetAsync(d_ws, 0, 28672, stream);     // zero s_buf + bn bins

    k_prep<<<(MM*260 + 255)/256, 256, 0, stream>>>(proj_w, proj_pad);

    dim3 g1(NN*FF, 2);
    k_beam_s<<<g1, 256, 0, stream>>>(x_real, x_imag, wq_r, wq_i, wk_r, wk_i, s_buf);

    k_softmax<<<1, 64, 0, stream>>>(s_buf, w_buf);

    k_vcompute<<<g1, 256, 0, stream>>>(x_real, x_imag, wv_r, wv_i, w_buf, vbuf);

    dim3 g3(NN, PCHUNK);
    k_proj<<<g3, 256, 0, stream>>>(vbuf, proj_pad, out, bn_sum, bn_sumsq);

    k_bnprep<<<1, 128, 0, stream>>>(bn_sum, bn_sumsq, bn_gamma, bn_beta, scale, shift);

    k_bnapply<<<(NN*TT*MM/4 + 255)/256, 256, 0, stream>>>(out, scale, shift);
}